// Round 6
// baseline (271.621 us; speedup 1.0000x reference)
//
#include <hip/hip_runtime.h>
#include <hip/hip_bf16.h>

// HelicalAttention on MI355X (gfx950).
// B=2,S=2048,E=1024,H=16,HD=64,HX=64,P=32. All heavy math in bf16 MFMA,
// fp32 accumulate. Score = (q/16)·k + (qs/8)·(ks/8) folded into one K=128
// contraction; log2(e) folded into Q so softmax uses raw exp2. Flash-style,
// no max subtraction (scores bounded).
// R6: attn is LDS-FREE and BARRIER-FREE. Q/K/V fragments load directly from
// global into registers (L1/L2-served); each wave owns 64 q-cols (q-reuse 2)
// and iterates ALL t, double-buffering K/V fragment registers across 64-t
// tiles (24 independent dwordx4 in flight under ~1500 cyc of MFMA). At
// 1 wave/SIMD the 512-reg budget absorbs this; latency hiding comes from
// ILP instead of TLP. den/O wave-private; epilogue den via __shfl.

typedef unsigned short u16;
typedef unsigned int u32;
typedef __attribute__((ext_vector_type(8))) __bf16 bf16x8;
typedef __attribute__((ext_vector_type(4))) float f32x4;
typedef __attribute__((ext_vector_type(16))) float f32x16;

union BFrag { u32 u[4]; bf16x8 b; };

__device__ __forceinline__ u16 f2b(float f) {
  u32 u = __float_as_uint(f);
  u32 r = (u + 0x7fffu + ((u >> 16) & 1u)) >> 16;
  return (u16)r;
}
__device__ __forceinline__ float b2f(u16 h) {
  return __uint_as_float(((u32)h) << 16);
}

__device__ __forceinline__ f32x4 mfma16(bf16x8 a, bf16x8 b, f32x4 c) {
  return __builtin_amdgcn_mfma_f32_16x16x32_bf16(a, b, c, 0, 0, 0);
}
__device__ __forceinline__ f32x16 mfma32(bf16x8 a, bf16x8 b, f32x16 c) {
  return __builtin_amdgcn_mfma_f32_32x32x16_bf16(a, b, c, 0, 0, 0);
}

// async global->LDS, 16B per lane. LDS dest = wave-uniform base + lane*16.
__device__ __forceinline__ void gld16(void* lds, const void* g) {
  __builtin_amdgcn_global_load_lds(
      (const __attribute__((address_space(1))) unsigned int*)g,
      (__attribute__((address_space(3))) unsigned int*)lds, 16, 0, 0);
}

#define LOG2E 1.4426950408889634f

// ---------------------------------------------------------------- cast -----
__global__ __launch_bounds__(256) void cast_kernel(
    const float* __restrict__ x,  const float* __restrict__ wq,
    const float* __restrict__ wk, const float* __restrict__ wv,
    const float* __restrict__ wo, const float* __restrict__ whel,
    u16* __restrict__ xb, u16* __restrict__ wb, u16* __restrict__ wob,
    u16* __restrict__ whb) {
  long long q = (long long)blockIdx.x * 256 + threadIdx.x;
  const float* s; u16* d; long long base;
  if (q < 1048576)      { s = x;    d = xb;            base = 0; }
  else if (q < 1310720) { s = wq;   d = wb;            base = 1048576; }
  else if (q < 1572864) { s = wk;   d = wb + 1048576;  base = 1310720; }
  else if (q < 1835008) { s = wv;   d = wb + 2097152;  base = 1572864; }
  else if (q < 2097152) { s = wo;   d = wob;           base = 1835008; }
  else                  { s = whel; d = whb;           base = 2097152; }
  long long e = (q - base) * 4;
  float4 v = *(const float4*)(s + e);
  ushort4 o;
  o.x = f2b(v.x); o.y = f2b(v.y); o.z = f2b(v.z); o.w = f2b(v.w);
  *(ushort4*)(d + e) = o;
}

// ------------------------------------------------------------ QKV GEMM -----
// which=0 -> Qcat[bh][s][0:64] = q*(log2e/16); which=1 -> Kcat = k;
// which=2 -> vT[bh][d][t] = v via LDS transpose (coalesced stores).
// Double-buffered LDS, prefetch-after-barrier pipeline (1 barrier/K-step).
__global__ __launch_bounds__(256, 3) void qkv_gemm(
    const u16* __restrict__ xb, const u16* __restrict__ wb,
    const float* __restrict__ bq, const float* __restrict__ bk,
    const float* __restrict__ bv,
    u16* __restrict__ Qcat, u16* __restrict__ Kcat, u16* __restrict__ vt) {
  __shared__ u16 Al[2][128][32];
  __shared__ u16 Bl[2][128][32];
  __shared__ u16 T[64][136];  // V transpose staging (epilogue only)
  const int nt = blockIdx.x, mt = blockIdx.y;
  const int which = nt >> 3;
  const int n0 = (nt & 7) << 7;
  const int m0 = mt << 7;
  const int tid = threadIdx.x;
  const int wave = tid >> 6, lane = tid & 63;
  const int g = lane >> 4, c15 = lane & 15;
  const int wm = wave & 1, wn = wave >> 1;
  const u16* Wp = wb + (long long)which * (1024 * 1024) + n0 * 1024;
  const u16* Ap = xb + m0 * 1024;
  const int srow = (wave * 64 + lane) >> 2;  // 0..63
  const int scol = (lane & 3) << 3;          // 0,8,16,24

  f32x4 acc[4][4];
#pragma unroll
  for (int i = 0; i < 4; i++)
#pragma unroll
    for (int j = 0; j < 4; j++) acc[i][j] = f32x4{0.f, 0.f, 0.f, 0.f};

  // prologue: stage k0=0 into buf 0
  gld16(&Al[0][srow][scol],      Ap + srow * 1024 + scol);
  gld16(&Al[0][64 + srow][scol], Ap + (64 + srow) * 1024 + scol);
  gld16(&Bl[0][srow][scol],      Wp + srow * 1024 + scol);
  gld16(&Bl[0][64 + srow][scol], Wp + (64 + srow) * 1024 + scol);

  for (int k0 = 0; k0 < 1024; k0 += 32) {
    const int c = (k0 >> 5) & 1;
    __syncthreads();  // waits DMA(k0); prefetch below had full compute to land
    if (k0 + 32 < 1024) {
      const int kn = k0 + 32;
      gld16(&Al[c ^ 1][srow][scol],      Ap + srow * 1024 + kn + scol);
      gld16(&Al[c ^ 1][64 + srow][scol], Ap + (64 + srow) * 1024 + kn + scol);
      gld16(&Bl[c ^ 1][srow][scol],      Wp + srow * 1024 + kn + scol);
      gld16(&Bl[c ^ 1][64 + srow][scol], Wp + (64 + srow) * 1024 + kn + scol);
    }
    bf16x8 a[4], b[4];
#pragma unroll
    for (int i = 0; i < 4; i++)
      a[i] = *(const bf16x8*)&Al[c][wm * 64 + i * 16 + c15][g * 8];
#pragma unroll
    for (int j = 0; j < 4; j++)
      b[j] = *(const bf16x8*)&Bl[c][wn * 64 + j * 16 + c15][g * 8];
#pragma unroll
    for (int i = 0; i < 4; i++)
#pragma unroll
      for (int j = 0; j < 4; j++) acc[i][j] = mfma16(a[i], b[j], acc[i][j]);
  }

  if (which == 2) {
#pragma unroll
    for (int half = 0; half < 2; ++half) {
      __syncthreads();
      if (wn == half) {
#pragma unroll
        for (int i = 0; i < 4; i++)
#pragma unroll
          for (int j = 0; j < 4; j++)
#pragma unroll
            for (int r = 0; r < 4; r++) {
              int nloc = j * 16 + c15;                  // 0..63
              int mloc = wm * 64 + i * 16 + g * 4 + r;  // 0..127
              float v = acc[i][j][r] + bv[n0 + half * 64 + nloc];
              T[nloc][mloc] = f2b(v);
            }
      }
      __syncthreads();
#pragma unroll
      for (int it = 0; it < 4; ++it) {
        int idx = it * 256 + tid;
        int row = idx >> 4;         // 0..63
        int cm = (idx & 15) * 8;    // 0..120
        int col = n0 + half * 64 + row;
        int hh = col >> 6, dd = col & 63;
        int m = m0 + cm;
        int bb2 = m >> 11, s = m & 2047;
        *(uint4*)&vt[(((bb2 * 16 + hh) * 64) + dd) * 2048 + s] =
            *(const uint4*)&T[row][cm];
      }
    }
    return;
  }

  const float* bias = (which == 0) ? bq : bk;
#pragma unroll
  for (int i = 0; i < 4; i++)
#pragma unroll
    for (int j = 0; j < 4; j++)
#pragma unroll
      for (int r = 0; r < 4; r++) {
        int row = m0 + wm * 64 + i * 16 + g * 4 + r;  // token 0..4095
        int col = n0 + wn * 64 + j * 16 + c15;        // 0..1023
        float v = acc[i][j][r] + bias[col];
        int bb = row >> 11, s = row & 2047;
        int hh = col >> 6, d = col & 63;
        if (which == 0) {
          Qcat[(((bb * 16 + hh) * 2048) + s) * 128 + d] =
              f2b(v * (0.0625f * LOG2E));
        } else {
          Kcat[(((bb * 16 + hh) * 2048) + s) * 128 + d] = f2b(v);
        }
      }
}

// ------------------------------------------------------------- helical -----
// Q-side outputs carry an extra log2e (K-side plain), matching qkv fold.
__global__ __launch_bounds__(256, 2) void helical_kernel(
    u16* __restrict__ Qcat, u16* __restrict__ Kcat,
    const u16* __restrict__ whb, const float* __restrict__ bhel) {
  __shared__ u16 A[2][2][64][32];  // [q/k][kq][row][32]
  __shared__ u16 Wl[2][64][32];    // Whel[h] bf16, [kq][e][32]
  const int sb = blockIdx.x, bh = blockIdx.y;
  const int h = bh & 15;
  const int s0 = sb << 6;
  const int tid = threadIdx.x;
  const int wave = tid >> 6, lane = tid & 63;
  const int g = lane >> 4, c15 = lane & 15;
  u16* Qb = Qcat + (long long)bh * (2048 * 128);
  u16* Kb = Kcat + (long long)bh * (2048 * 128);

#pragma unroll
  for (int it = 0; it < 2; ++it) {  // stage Whel[h]
    int cidx = it * 256 + tid;
    int e = cidx >> 3, ds = (cidx & 7) << 3;
    uint4 vv = *(const uint4*)(whb + h * 4096 + e * 64 + ds);
    *(uint4*)&Wl[ds >> 5][e][ds & 31] = vv;
  }
#pragma unroll
  for (int it = 0; it < 4; ++it) {  // stage q (undo fold) and k rows
    int cidx = it * 256 + tid;
    int which = cidx >> 9;
    int r = (cidx >> 3) & 63;
    int ds = (cidx & 7) << 3;
    const u16* src = (which ? Kb : Qb) + (s0 + r) * 128 + ds;
    uint4 vv = *(const uint4*)src;
    if (which == 0) {
      u16 tmp[8];
      *(uint4*)tmp = vv;
#pragma unroll
      for (int q = 0; q < 8; ++q)
        tmp[q] = f2b(b2f(tmp[q]) * (16.0f / LOG2E));
      vv = *(uint4*)tmp;
    }
    *(uint4*)&A[which][ds >> 5][r][ds & 31] = vv;
  }
  __syncthreads();

  const int which = wave >> 1, hf = wave & 1;
  f32x4 acc[2][4];
#pragma unroll
  for (int i = 0; i < 2; i++)
#pragma unroll
    for (int j = 0; j < 4; j++) acc[i][j] = f32x4{0.f, 0.f, 0.f, 0.f};
#pragma unroll
  for (int kq = 0; kq < 2; ++kq) {
    bf16x8 a0 = *(const bf16x8*)&A[which][kq][hf * 32 + c15][g * 8];
    bf16x8 a1 = *(const bf16x8*)&A[which][kq][hf * 32 + 16 + c15][g * 8];
#pragma unroll
    for (int j = 0; j < 4; ++j) {
      bf16x8 bb = *(const bf16x8*)&Wl[kq][j * 16 + c15][g * 8];
      acc[0][j] = mfma16(a0, bb, acc[0][j]);
      acc[1][j] = mfma16(a1, bb, acc[1][j]);
    }
  }
  u16* Dst = which ? Kb : Qb;
  const float oscale = which ? 0.125f : (0.125f * LOG2E);
#pragma unroll
  for (int i = 0; i < 2; ++i)
#pragma unroll
    for (int j = 0; j < 4; ++j)
#pragma unroll
      for (int r = 0; r < 4; ++r) {
        int s_loc = hf * 32 + i * 16 + g * 4 + r;
        int e = j * 16 + c15;
        float v = acc[i][j][r] + bhel[h * 64 + e];
        float pp = __shfl_xor(v, 1);  // pair partner (e^1), same row
        float nn = sqrtf(v * v + pp * pp);
        float o = v / fmaxf(nn, 1e-12f) * oscale;
        int s = s0 + s_loc;
        int u = s >> 1, c2 = s & 1;
        int row_out = ((e & 1) ? 1024 : 0) + u;
        int col_out = 64 + (e & ~1) + c2;
        Dst[row_out * 128 + col_out] = f2b(o);
      }
}

// ----------------------------------------------------------- attention -----
// LDS-free / barrier-free. Block = 128 threads (2 independent waves), grid
// (16 qg, 32 bh) = 512 blocks -> 4 waves/CU at 1 wave/SIMD (512-reg budget).
// Wave w covers q = [qg*128 + 64w, +64) (q-reuse 2) and iterates ALL 32
// t-tiles of 64, double-buffering K/V fragment REGISTERS (24 dwordx4 per
// tile in flight under ~1500 cyc of MFMA). S^T = K·Q^T (32 mfma32), exp2,
// shfl-relayout C->A, PV (16 mfma32). den wave-private; epilogue den
// broadcast via __shfl; O scaled by rcp(den) and stored.
__global__ __launch_bounds__(128, 1) void attn_kernel(
    const u16* __restrict__ Qcat, const u16* __restrict__ Kcat,
    const u16* __restrict__ vt, u16* __restrict__ AO) {
  const int qg = blockIdx.x, bh = blockIdx.y;
  const int bb = bh >> 4, h = bh & 15;
  const int tid = threadIdx.x;
  const int w = tid >> 6, lane = tid & 63;
  const int l31 = lane & 31, l5 = lane >> 5;
  const int qw = qg * 128 + w * 64;  // wave's q-base (covers 64 q)
  const u16* Qb = Qcat + (long long)bh * (2048 * 128);
  const u16* Kb = Kcat + (long long)bh * (2048 * 128);
  const u16* Vb = vt + (long long)bh * (64 * 2048);

  // Q B-frags: n=l31 -> q = qw + 32*qh + l31; k = ks*16 + l5*8 + j
  bf16x8 qf[2][8];
#pragma unroll
  for (int qh = 0; qh < 2; ++qh) {
    const u16* qrow = Qb + (qw + 32 * qh + l31) * 128 + l5 * 8;
#pragma unroll
    for (int ks = 0; ks < 8; ++ks)
      qf[qh][ks] = *(const bf16x8*)(qrow + ks * 16);
  }

  // per-lane base pointers for K (A-frag) and V (B-frag) streams
  const u16* kbase = Kb + l31 * 128 + l5 * 8;   // + t*8192 + sl*4096 + ks*16
  const u16* vbase = Vb + l31 * 2048 + l5 * 8;  // + dq*65536 + t*64 + c*16

  f32x16 accO[2][2];  // [qh][dq]
#pragma unroll
  for (int a = 0; a < 2; ++a)
#pragma unroll
    for (int b = 0; b < 2; ++b)
#pragma unroll
      for (int i = 0; i < 16; ++i) accO[a][b][i] = 0.f;
  float den[2] = {0.f, 0.f};

  auto ldt = [&](int t, bf16x8 (&kf)[2][8], bf16x8 (&vf)[2][4]) {
    const u16* kt = kbase + t * 8192;
#pragma unroll
    for (int sl = 0; sl < 2; ++sl)
#pragma unroll
      for (int ks = 0; ks < 8; ++ks)
        kf[sl][ks] = *(const bf16x8*)(kt + sl * 4096 + ks * 16);
    const u16* vtp = vbase + t * 64;
#pragma unroll
    for (int dq = 0; dq < 2; ++dq)
#pragma unroll
      for (int c = 0; c < 4; ++c)
        vf[dq][c] = *(const bf16x8*)(vtp + dq * 65536 + c * 16);
  };

  auto step = [&](bf16x8 (&kf)[2][8], bf16x8 (&vf)[2][4]) {
    // ---- S^T for both 32-t slices (32 mfma back-to-back; q-reuse 2)
    f32x16 aS[2][2];  // [slice][qh]
#pragma unroll
    for (int sl = 0; sl < 2; ++sl)
#pragma unroll
      for (int qh = 0; qh < 2; ++qh)
#pragma unroll
        for (int i = 0; i < 16; ++i) aS[sl][qh][i] = 0.f;
#pragma unroll
    for (int sl = 0; sl < 2; ++sl)
#pragma unroll
      for (int ks = 0; ks < 8; ++ks) {
        bf16x8 ak = kf[sl][ks];
        aS[sl][0] = mfma32(ak, qf[0][ks], aS[sl][0]);
        aS[sl][1] = mfma32(ak, qf[1][ks], aS[sl][1]);
      }
    // ---- per slice: exp2 -> pack -> shfl relayout -> PV
#pragma unroll
    for (int sl = 0; sl < 2; ++sl) {
      BFrag PA[2][2];  // [qh][kstep]
#pragma unroll
      for (int qh = 0; qh < 2; ++qh) {
        u32 D0[2], D1[2], D2[2], D3[2];
#pragma unroll
        for (int rr = 0; rr < 4; ++rr) {
          float p0 = __builtin_amdgcn_exp2f(aS[sl][qh][4 * rr + 0]);
          float p1 = __builtin_amdgcn_exp2f(aS[sl][qh][4 * rr + 1]);
          float p2 = __builtin_amdgcn_exp2f(aS[sl][qh][4 * rr + 2]);
          float p3 = __builtin_amdgcn_exp2f(aS[sl][qh][4 * rr + 3]);
          den[qh] += (p0 + p1) + (p2 + p3);
          u32 lo = (__float_as_uint(p0) >> 16) |
                   (__float_as_uint(p1) & 0xffff0000u);
          u32 hi = (__float_as_uint(p2) >> 16) |
                   (__float_as_uint(p3) & 0xffff0000u);
          if (rr == 0) { D0[0] = lo; D0[1] = hi; }
          else if (rr == 1) { D1[0] = lo; D1[1] = hi; }
          else if (rr == 2) { D2[0] = lo; D2[1] = hi; }
          else { D3[0] = lo; D3[1] = hi; }
        }
        u32 e00 = __shfl_xor((int)D0[0], 32), e01 = __shfl_xor((int)D0[1], 32);
        u32 e10 = __shfl_xor((int)D1[0], 32), e11 = __shfl_xor((int)D1[1], 32);
        u32 e20 = __shfl_xor((int)D2[0], 32), e21 = __shfl_xor((int)D2[1], 32);
        u32 e30 = __shfl_xor((int)D3[0], 32), e31 = __shfl_xor((int)D3[1], 32);
        PA[qh][0].u[0] = l5 ? e10 : D0[0];
        PA[qh][0].u[1] = l5 ? e11 : D0[1];
        PA[qh][0].u[2] = l5 ? D1[0] : e00;
        PA[qh][0].u[3] = l5 ? D1[1] : e01;
        PA[qh][1].u[0] = l5 ? e30 : D2[0];
        PA[qh][1].u[1] = l5 ? e31 : D2[1];
        PA[qh][1].u[2] = l5 ? D3[0] : e20;
        PA[qh][1].u[3] = l5 ? D3[1] : e21;
      }
#pragma unroll
      for (int dq = 0; dq < 2; ++dq) {
        bf16x8 bv0 = vf[dq][sl * 2 + 0];
        bf16x8 bv1 = vf[dq][sl * 2 + 1];
        accO[0][dq] = mfma32(PA[0][0].b, bv0, accO[0][dq]);
        accO[0][dq] = mfma32(PA[0][1].b, bv1, accO[0][dq]);
        accO[1][dq] = mfma32(PA[1][0].b, bv0, accO[1][dq]);
        accO[1][dq] = mfma32(PA[1][1].b, bv1, accO[1][dq]);
      }
    }
  };

  // register-double-buffered tile loop (no LDS, no barriers)
  bf16x8 kfA[2][8], vfA[2][4], kfB[2][8], vfB[2][4];
  ldt(0, kfA, vfA);
  for (int t = 0; t < 32; t += 2) {
    ldt(t + 1, kfB, vfB);
    step(kfA, vfA);
    if (t + 2 < 32) ldt(t + 2, kfA, vfA);
    step(kfB, vfB);
  }

  // ---- epilogue: complete den (cross-l5), broadcast per row, scale, store
  den[0] += __shfl_xor(den[0], 32);
  den[1] += __shfl_xor(den[1], 32);
#pragma unroll
  for (int qh = 0; qh < 2; ++qh)
#pragma unroll
    for (int r = 0; r < 16; ++r) {
      int rowl = (r & 3) + 8 * (r >> 2) + 4 * l5;  // q-local within 32-block
      float dr = __shfl(den[qh], rowl);
      float inv = __builtin_amdgcn_rcpf(dr);
      int q = qw + 32 * qh + rowl;
      long long base = ((long long)(bb * 2048 + q) * 1024) + h * 64;
      AO[base + l31]      = f2b(accO[qh][0][r] * inv);
      AO[base + 32 + l31] = f2b(accO[qh][1][r] * inv);
    }
}

// ----------------------------------------------------------- out GEMM -----
// Double-buffered prefetch-after-barrier pipeline (1 barrier/K-step).
__global__ __launch_bounds__(256, 2) void out_gemm(
    const u16* __restrict__ AO, const u16* __restrict__ wob,
    const float* __restrict__ bo, float* __restrict__ out) {
  __shared__ u16 Al[2][128][32];
  __shared__ u16 Bl[2][128][32];
  const int n0 = blockIdx.x << 7;
  const int m0 = blockIdx.y << 7;
  const int tid = threadIdx.x;
  const int wave = tid >> 6, lane = tid & 63;
  const int g = lane >> 4, c15 = lane & 15;
  const int wm = wave & 1, wn = wave >> 1;
  const u16* Wp = wob + n0 * 1024;
  const u16* Ap = AO + m0 * 1024;
  const int srow = (wave * 64 + lane) >> 2;
  const int scol = (lane & 3) << 3;

  f32x4 acc[4][4];
#pragma unroll
  for (int i = 0; i < 4; i++)
#pragma unroll
    for (int j = 0; j < 4; j++) acc[i][j] = f32x4{0.f, 0.f, 0.f, 0.f};

  gld16(&Al[0][srow][scol],      Ap + srow * 1024 + scol);
  gld16(&Al[0][64 + srow][scol], Ap + (64 + srow) * 1024 + scol);
  gld16(&Bl[0][srow][scol],      Wp + srow * 1024 + scol);
  gld16(&Bl[0][64 + srow][scol], Wp + (64 + srow) * 1024 + scol);

  for (int k0 = 0; k0 < 1024; k0 += 32) {
    const int c = (k0 >> 5) & 1;
    __syncthreads();
    if (k0 + 32 < 1024) {
      const int kn = k0 + 32;
      gld16(&Al[c ^ 1][srow][scol],      Ap + srow * 1024 + kn + scol);
      gld16(&Al[c ^ 1][64 + srow][scol], Ap + (64 + srow) * 1024 + kn + scol);
      gld16(&Bl[c ^ 1][srow][scol],      Wp + srow * 1024 + kn + scol);
      gld16(&Bl[c ^ 1][64 + srow][scol], Wp + (64 + srow) * 1024 + kn + scol);
    }
    bf16x8 a[4], b[4];
#pragma unroll
    for (int i = 0; i < 4; i++)
      a[i] = *(const bf16x8*)&Al[c][wm * 64 + i * 16 + c15][g * 8];
#pragma unroll
    for (int j = 0; j < 4; j++)
      b[j] = *(const bf16x8*)&Bl[c][wn * 64 + j * 16 + c15][g * 8];
#pragma unroll
    for (int i = 0; i < 4; i++)
#pragma unroll
      for (int j = 0; j < 4; j++) acc[i][j] = mfma16(a[i], b[j], acc[i][j]);
  }
#pragma unroll
  for (int i = 0; i < 4; i++)
#pragma unroll
    for (int j = 0; j < 4; j++)
#pragma unroll
      for (int r = 0; r < 4; r++) {
        int row = m0 + wm * 64 + i * 16 + g * 4 + r;
        int col = n0 + wn * 64 + j * 16 + c15;
        out[row * 1024 + col] = acc[i][j][r] + bo[col];
      }
}

// -------------------------------------------------------------- launch -----
extern "C" void kernel_launch(void* const* d_in, const int* in_sizes, int n_in,
                              void* d_out, int out_size, void* d_ws,
                              size_t ws_size, hipStream_t stream) {
  const float* x    = (const float*)d_in[0];
  const float* Wq   = (const float*)d_in[1];
  const float* bq   = (const float*)d_in[2];
  const float* Wk   = (const float*)d_in[3];
  const float* bk   = (const float*)d_in[4];
  const float* Wv   = (const float*)d_in[5];
  const float* bv   = (const float*)d_in[6];
  const float* Wo   = (const float*)d_in[7];
  const float* bo   = (const float*)d_in[8];
  const float* Whel = (const float*)d_in[9];
  const float* bhel = (const float*)d_in[10];
  float* out = (float*)d_out;

  char* ws = (char*)d_ws;
  u16* xb   = (u16*)(ws + 0);                  //  8 MB
  u16* wb   = (u16*)(ws + 8388608);            //  6 MB (Wq|Wk|Wv)
  u16* wob  = (u16*)(ws + 14680064);           //  2 MB
  u16* whb  = (u16*)(ws + 16777216);           //  128 KB
  u16* Qcat = (u16*)(ws + 16908288);           // 16 MB  [bh][s][128]
  u16* Kcat = (u16*)(ws + 33685504);           // 16 MB
  u16* vt   = (u16*)(ws + 50462720);           //  8 MB  [bh][d][t]
  u16* AO   = (u16*)(ws + 58851328);           //  8 MB  (total ~64.1 MB)

  cast_kernel<<<dim3(8256), dim3(256), 0, stream>>>(x, Wq, Wk, Wv, Wo, Whel,
                                                    xb, wb, wob, whb);
  qkv_gemm<<<dim3(24, 32), dim3(256), 0, stream>>>(xb, wb, bq, bk, bv, Qcat,
                                                   Kcat, vt);
  helical_kernel<<<dim3(32, 32), dim3(256), 0, stream>>>(Qcat, Kcat, whb,
                                                         bhel);
  attn_kernel<<<dim3(16, 32), dim3(128), 0, stream>>>(Qcat, Kcat, vt, AO);
  out_gemm<<<dim3(8, 32), dim3(256), 0, stream>>>(AO, wob, bo, out);
}

// Round 7
// 227.534 us; speedup vs baseline: 1.1938x; 1.1938x over previous
//
#include <hip/hip_runtime.h>
#include <hip/hip_bf16.h>

// HelicalAttention on MI355X (gfx950).
// B=2,S=2048,E=1024,H=16,HD=64,HX=64,P=32. All heavy math in bf16 MFMA,
// fp32 accumulate. Score = (q/16)·k + (qs/8)·(ks/8) folded into one K=128
// contraction; log2(e) folded into Q so softmax uses raw exp2. Flash-style,
// no max subtraction (scores bounded).
// R7: helical projection FUSED into qkv epilogue (block spans 2 full heads;
// acc registers already hold the 64x64 A-operand) — helical kernel deleted.
// out_gemm retiled to 128x64 (grid 512 = 2 blocks/CU, was 1). attn = R4
// structure verbatim (single-barrier pipelined K-loop, register P).

typedef unsigned short u16;
typedef unsigned int u32;
typedef __attribute__((ext_vector_type(8))) __bf16 bf16x8;
typedef __attribute__((ext_vector_type(4))) float f32x4;
typedef __attribute__((ext_vector_type(16))) float f32x16;

union BFrag { u32 u[4]; bf16x8 b; };

__device__ __forceinline__ u16 f2b(float f) {
  u32 u = __float_as_uint(f);
  u32 r = (u + 0x7fffu + ((u >> 16) & 1u)) >> 16;
  return (u16)r;
}
__device__ __forceinline__ float b2f(u16 h) {
  return __uint_as_float(((u32)h) << 16);
}

__device__ __forceinline__ f32x4 mfma16(bf16x8 a, bf16x8 b, f32x4 c) {
  return __builtin_amdgcn_mfma_f32_16x16x32_bf16(a, b, c, 0, 0, 0);
}
__device__ __forceinline__ f32x16 mfma32(bf16x8 a, bf16x8 b, f32x16 c) {
  return __builtin_amdgcn_mfma_f32_32x32x16_bf16(a, b, c, 0, 0, 0);
}

// async global->LDS, 16B per lane. LDS dest = wave-uniform base + lane*16.
__device__ __forceinline__ void gld16(void* lds, const void* g) {
  __builtin_amdgcn_global_load_lds(
      (const __attribute__((address_space(1))) unsigned int*)g,
      (__attribute__((address_space(3))) unsigned int*)lds, 16, 0, 0);
}

#define LOG2E 1.4426950408889634f

// ---------------------------------------------------------------- cast -----
__global__ __launch_bounds__(256) void cast_kernel(
    const float* __restrict__ x,  const float* __restrict__ wq,
    const float* __restrict__ wk, const float* __restrict__ wv,
    const float* __restrict__ wo, const float* __restrict__ whel,
    u16* __restrict__ xb, u16* __restrict__ wb, u16* __restrict__ wob,
    u16* __restrict__ whb) {
  long long q = (long long)blockIdx.x * 256 + threadIdx.x;
  const float* s; u16* d; long long base;
  if (q < 1048576)      { s = x;    d = xb;            base = 0; }
  else if (q < 1310720) { s = wq;   d = wb;            base = 1048576; }
  else if (q < 1572864) { s = wk;   d = wb + 1048576;  base = 1310720; }
  else if (q < 1835008) { s = wv;   d = wb + 2097152;  base = 1572864; }
  else if (q < 2097152) { s = wo;   d = wob;           base = 1835008; }
  else                  { s = whel; d = whb;           base = 2097152; }
  long long e = (q - base) * 4;
  float4 v = *(const float4*)(s + e);
  ushort4 o;
  o.x = f2b(v.x); o.y = f2b(v.y); o.z = f2b(v.z); o.w = f2b(v.w);
  *(ushort4*)(d + e) = o;
}

// ------------------------------------------------------- QKV GEMM + hel ----
// which=0 -> Qcat[bh][s][0:64] = q*(log2e/16); which=1 -> Kcat = k;
// which=2 -> vT[bh][d][t] = v via LDS transpose (coalesced stores).
// Fused helical epilogue (which 0/1): each wave's 64x64 acc quadrant is one
// full head x 64 tokens; hel = acc·Whel[h]^T + bhel -> pair-normalize ->
// scramble -> write cols [64:128). Two 32-token half-passes keep LDS <= main.
__global__ __launch_bounds__(256, 3) void qkv_gemm(
    const u16* __restrict__ xb, const u16* __restrict__ wb,
    const float* __restrict__ bq, const float* __restrict__ bk,
    const float* __restrict__ bv, const u16* __restrict__ whb,
    const float* __restrict__ bhel,
    u16* __restrict__ Qcat, u16* __restrict__ Kcat, u16* __restrict__ vt) {
  union SM {
    struct { u16 Al[2][128][32]; u16 Bl[2][128][32]; u16 T[64][136]; } m;
    struct { u16 Th[4][32][80]; u16 Whl[2][64][80]; } e;  // 40960 < 50176
  };
  __shared__ SM sm;
  const int nt = blockIdx.x, mt = blockIdx.y;
  const int which = nt >> 3;
  const int n0 = (nt & 7) << 7;
  const int m0 = mt << 7;
  const int tid = threadIdx.x;
  const int wave = tid >> 6, lane = tid & 63;
  const int g = lane >> 4, c15 = lane & 15;
  const int wm = wave & 1, wn = wave >> 1;
  const u16* Wp = wb + (long long)which * (1024 * 1024) + n0 * 1024;
  const u16* Ap = xb + m0 * 1024;
  const int srow = (wave * 64 + lane) >> 2;  // 0..63
  const int scol = (lane & 3) << 3;          // 0,8,16,24

  f32x4 acc[4][4];
#pragma unroll
  for (int i = 0; i < 4; i++)
#pragma unroll
    for (int j = 0; j < 4; j++) acc[i][j] = f32x4{0.f, 0.f, 0.f, 0.f};

  // prologue: stage k0=0 into buf 0
  gld16(&sm.m.Al[0][srow][scol],      Ap + srow * 1024 + scol);
  gld16(&sm.m.Al[0][64 + srow][scol], Ap + (64 + srow) * 1024 + scol);
  gld16(&sm.m.Bl[0][srow][scol],      Wp + srow * 1024 + scol);
  gld16(&sm.m.Bl[0][64 + srow][scol], Wp + (64 + srow) * 1024 + scol);

  for (int k0 = 0; k0 < 1024; k0 += 32) {
    const int c = (k0 >> 5) & 1;
    __syncthreads();  // waits DMA(k0); prefetch below had full compute to land
    if (k0 + 32 < 1024) {
      const int kn = k0 + 32;
      gld16(&sm.m.Al[c ^ 1][srow][scol],      Ap + srow * 1024 + kn + scol);
      gld16(&sm.m.Al[c ^ 1][64 + srow][scol],
            Ap + (64 + srow) * 1024 + kn + scol);
      gld16(&sm.m.Bl[c ^ 1][srow][scol],      Wp + srow * 1024 + kn + scol);
      gld16(&sm.m.Bl[c ^ 1][64 + srow][scol],
            Wp + (64 + srow) * 1024 + kn + scol);
    }
    bf16x8 a[4], b[4];
#pragma unroll
    for (int i = 0; i < 4; i++)
      a[i] = *(const bf16x8*)&sm.m.Al[c][wm * 64 + i * 16 + c15][g * 8];
#pragma unroll
    for (int j = 0; j < 4; j++)
      b[j] = *(const bf16x8*)&sm.m.Bl[c][wn * 64 + j * 16 + c15][g * 8];
#pragma unroll
    for (int i = 0; i < 4; i++)
#pragma unroll
      for (int j = 0; j < 4; j++) acc[i][j] = mfma16(a[i], b[j], acc[i][j]);
  }

  if (which == 2) {
#pragma unroll
    for (int half = 0; half < 2; ++half) {
      __syncthreads();
      if (wn == half) {
#pragma unroll
        for (int i = 0; i < 4; i++)
#pragma unroll
          for (int j = 0; j < 4; j++)
#pragma unroll
            for (int r = 0; r < 4; r++) {
              int nloc = j * 16 + c15;                  // 0..63
              int mloc = wm * 64 + i * 16 + g * 4 + r;  // 0..127
              float v = acc[i][j][r] + bv[n0 + half * 64 + nloc];
              sm.m.T[nloc][mloc] = f2b(v);
            }
      }
      __syncthreads();
#pragma unroll
      for (int it = 0; it < 4; ++it) {
        int idx = it * 256 + tid;
        int row = idx >> 4;         // 0..63
        int cm = (idx & 15) * 8;    // 0..120
        int col = n0 + half * 64 + row;
        int hh = col >> 6, dd = col & 63;
        int m = m0 + cm;
        int bb2 = m >> 11, s = m & 2047;
        *(uint4*)&vt[(((bb2 * 16 + hh) * 64) + dd) * 2048 + s] =
            *(const uint4*)&sm.m.T[row][cm];
      }
    }
    return;
  }

  // ---------------- fused helical epilogue (which 0 or 1) ----------------
  const float* bias = (which == 0) ? bq : bk;
  const float fold = (which == 0) ? (0.0625f * LOG2E) : 1.0f;
  const float osc  = (which == 0) ? (0.125f * LOG2E) : 0.125f;
  const int hsel = (n0 >> 6) + wn;  // wave's head (block spans 2 heads)
  u16* Dst = ((which == 0) ? Qcat : Kcat);

  __syncthreads();  // all main-loop LDS reads done; safe to repurpose
  // stage Whel (bf16) for the block's 2 heads into [64][80] (16B rows OK)
#pragma unroll
  for (int it = 0; it < 4; ++it) {
    int idx = it * 256 + tid;         // 0..1023 chunk slots of 8 u16
    int hh = idx >> 9;
    int e = (idx >> 3) & 63;
    int ck = idx & 7;
    int hg = (n0 >> 6) + hh;
    *(uint4*)&sm.e.Whl[hh][e][ck * 8] =
        *(const uint4*)(whb + hg * 4096 + e * 64 + ck * 8);
  }
  __syncthreads();

#pragma unroll
  for (int half = 0; half < 2; ++half) {
    // write main output (cols [0:64)) + per-wave Th tile (raw bf16, no fold)
#pragma unroll
    for (int i2 = 0; i2 < 2; ++i2) {
      int i = half * 2 + i2;
#pragma unroll
      for (int j = 0; j < 4; ++j)
#pragma unroll
        for (int r = 0; r < 4; ++r) {
          int row = m0 + wm * 64 + i * 16 + g * 4 + r;  // token 0..4095
          int col = n0 + wn * 64 + j * 16 + c15;
          float vraw = acc[i][j][r] + bias[col];
          int bb = row >> 11, s = row & 2047;
          int d = col & 63;
          Dst[(((long long)(bb * 16 + hsel) * 2048) + s) * 128 + d] =
              f2b(vraw * fold);
          sm.e.Th[wave][i2 * 16 + g * 4 + r][j * 16 + c15] = f2b(vraw);
        }
    }
    // hel = Th(32 tok x 64 d) · Whel[h]^T (64 e x 64 d)  [wave-private Th]
    f32x4 hacc[2][4];
#pragma unroll
    for (int mf = 0; mf < 2; ++mf)
#pragma unroll
      for (int nf = 0; nf < 4; ++nf) hacc[mf][nf] = f32x4{0.f, 0.f, 0.f, 0.f};
#pragma unroll
    for (int kh = 0; kh < 2; ++kh) {
      bf16x8 a0 = *(const bf16x8*)&sm.e.Th[wave][c15][kh * 32 + g * 8];
      bf16x8 a1 = *(const bf16x8*)&sm.e.Th[wave][16 + c15][kh * 32 + g * 8];
#pragma unroll
      for (int nf = 0; nf < 4; ++nf) {
        bf16x8 bwh =
            *(const bf16x8*)&sm.e.Whl[wn][nf * 16 + c15][kh * 32 + g * 8];
        hacc[0][nf] = mfma16(a0, bwh, hacc[0][nf]);
        hacc[1][nf] = mfma16(a1, bwh, hacc[1][nf]);
      }
    }
    // + bhel, pair-normalize (partner e^1 = lane^1), scramble, write [64:128)
#pragma unroll
    for (int mf = 0; mf < 2; ++mf)
#pragma unroll
      for (int nf = 0; nf < 4; ++nf)
#pragma unroll
        for (int r = 0; r < 4; ++r) {
          int e = nf * 16 + c15;
          float v = hacc[mf][nf][r] + bhel[hsel * 64 + e];
          float pp = __shfl_xor(v, 1);
          float nn = sqrtf(v * v + pp * pp);
          float o = v / fmaxf(nn, 1e-12f) * osc;
          int tok = m0 + wm * 64 + half * 32 + mf * 16 + g * 4 + r;
          int bb = tok >> 11, s = tok & 2047;
          int row_out = ((e & 1) ? 1024 : 0) + (s >> 1);
          int col_out = 64 + (e & ~1) + (s & 1);
          Dst[(((long long)(bb * 16 + hsel) * 2048) + row_out) * 128 +
              col_out] = f2b(o);
        }
  }
}

// ----------------------------------------------------------- attention -----
// R4 structure: per (bh, 128-q tile), 8 waves: wq=w&3, wt=w>>2 (t half).
// Pipelined single-barrier K-loop over 32 tiles of 64 t; P in registers
// (shfl_xor(32) C->A relayout); cross-wt O partial sum at end via LDS.
// LDS 49 KB; grid 512 = 2 blocks/CU.
__global__ __launch_bounds__(512, 4) void attn_kernel(
    const u16* __restrict__ Qcat, const u16* __restrict__ Kcat,
    const u16* __restrict__ vt, u16* __restrict__ AO) {
  __shared__ u16 Kl[2][64][128];   // [buf][t-row][cat 16 chunks, swizzled]
  __shared__ u16 Vl[2][64][64];    // [buf][d-row][t 8 chunks, swizzled]
  __shared__ float denl[2][128];   // [wt][q-local]
  const int qt = blockIdx.x, bh = blockIdx.y;
  const int bb = bh >> 4, h = bh & 15;
  const int q0 = qt << 7;
  const int tid = threadIdx.x;
  const int w = tid >> 6, lane = tid & 63;
  const int wq = w & 3, wt = w >> 2;
  const int l31 = lane & 31, l5 = lane >> 5;
  const u16* Qb = Qcat + (long long)bh * (2048 * 128);
  const u16* Kb = Kcat + (long long)bh * (2048 * 128);
  const u16* Vb = vt + (long long)bh * (64 * 2048);

  // Q B-frags: n = l31 -> q = q0+32wq+l31; k = ks*16+l5*8+j
  bf16x8 qf[8];
  {
    const u16* qrow = Qb + (q0 + 32 * wq + l31) * 128 + l5 * 8;
#pragma unroll
    for (int ks = 0; ks < 8; ++ks) qf[ks] = *(const bf16x8*)(qrow + ks * 16);
  }

  // staging address precompute (XOR-swizzled 16B chunks)
  const int ll = tid;                 // 0..511
  const int krow0 = ll >> 4;          // pass 0: rows 0..31
  const int kp = ll & 15;
  const int ksrc0 = (kp & 8) | ((kp & 7) ^ (krow0 & 7));
  const int krow1 = 32 + krow0;       // pass 1: rows 32..63
  const int ksrc1 = (kp & 8) | ((kp & 7) ^ (krow1 & 7));
  const int vd = ll >> 3;
  const int vsrc = (ll & 7) ^ (vd & 7);

  // prologue: stage tile 0 into buf 0
  gld16(((u16*)Kl[0]) + ll * 8,        Kb + krow0 * 128 + ksrc0 * 8);
  gld16(((u16*)Kl[0]) + 4096 + ll * 8, Kb + krow1 * 128 + ksrc1 * 8);
  gld16(((u16*)Vl[0]) + ll * 8,        Vb + vd * 2048 + vsrc * 8);

  f32x16 accO0, accO1;
#pragma unroll
  for (int i = 0; i < 16; ++i) { accO0[i] = 0.f; accO1[i] = 0.f; }
  float den = 0.f;

  const int krow = 32 * wt + l31;  // S-phase A row (t-local)
  const int kr7 = krow & 7;

  for (int t = 0; t < 32; ++t) {
    const int cur = t & 1;
    __syncthreads();  // DMA(tile t) complete; readers of buf cur^1 done
    if (t + 1 < 32) {
      const int t1 = (t + 1) << 6;
      u16* Kd = (u16*)Kl[cur ^ 1];
      gld16(Kd + ll * 8,        Kb + (t1 + krow0) * 128 + ksrc0 * 8);
      gld16(Kd + 4096 + ll * 8, Kb + (t1 + krow1) * 128 + ksrc1 * 8);
      gld16(((u16*)Vl[cur ^ 1]) + ll * 8, Vb + vd * 2048 + t1 + vsrc * 8);
    }

    // ---- S^T[t-local 32wt..][q 32wq..] : 8 k-steps of 16 over cat=128
    f32x16 accS;
#pragma unroll
    for (int i = 0; i < 16; ++i) accS[i] = 0.f;
#pragma unroll
    for (int ks = 0; ks < 8; ++ks) {
      int lc = 2 * ks + l5;
      int p = (lc & 8) | ((lc & 7) ^ kr7);
      bf16x8 ak = *(const bf16x8*)&Kl[cur][krow][p * 8];
      accS = mfma32(ak, qf[ks], accS);
    }

    // ---- exp2 -> packed bf16 P (regs); per-lane den partial
    u32 D0[2], D1[2], D2[2], D3[2];
#pragma unroll
    for (int rr = 0; rr < 4; ++rr) {
      float p0 = __builtin_amdgcn_exp2f(accS[4 * rr + 0]);
      float p1 = __builtin_amdgcn_exp2f(accS[4 * rr + 1]);
      float p2 = __builtin_amdgcn_exp2f(accS[4 * rr + 2]);
      float p3 = __builtin_amdgcn_exp2f(accS[4 * rr + 3]);
      den += (p0 + p1) + (p2 + p3);
      u32 lo = (__float_as_uint(p0) >> 16) | (__float_as_uint(p1) & 0xffff0000u);
      u32 hi = (__float_as_uint(p2) >> 16) | (__float_as_uint(p3) & 0xffff0000u);
      if (rr == 0) { D0[0] = lo; D0[1] = hi; }
      else if (rr == 1) { D1[0] = lo; D1[1] = hi; }
      else if (rr == 2) { D2[0] = lo; D2[1] = hi; }
      else { D3[0] = lo; D3[1] = hi; }
    }
    // cross-l5 exchange: build A-frags (m=q, k=t-local within own half)
    BFrag A0, A1;
    {
      u32 e00 = __shfl_xor((int)D0[0], 32), e01 = __shfl_xor((int)D0[1], 32);
      u32 e10 = __shfl_xor((int)D1[0], 32), e11 = __shfl_xor((int)D1[1], 32);
      u32 e20 = __shfl_xor((int)D2[0], 32), e21 = __shfl_xor((int)D2[1], 32);
      u32 e30 = __shfl_xor((int)D3[0], 32), e31 = __shfl_xor((int)D3[1], 32);
      A0.u[0] = l5 ? e10 : D0[0];
      A0.u[1] = l5 ? e11 : D0[1];
      A0.u[2] = l5 ? D1[0] : e00;
      A0.u[3] = l5 ? D1[1] : e01;
      A1.u[0] = l5 ? e30 : D2[0];
      A1.u[1] = l5 ? e31 : D2[1];
      A1.u[2] = l5 ? D3[0] : e20;
      A1.u[3] = l5 ? D3[1] : e21;
    }

    // ---- O_partial[q 32wq..][d 0..63] += P · V over OWN t-half (k=32)
#pragma unroll
    for (int dq = 0; dq < 2; ++dq) {
      int d = 32 * dq + l31;
      int d7 = d & 7;
#pragma unroll
      for (int ks = 0; ks < 2; ++ks) {
        int lc = 4 * wt + 2 * ks + l5;
        bf16x8 bvf = *(const bf16x8*)&Vl[cur][d][((lc ^ d7) & 7) * 8];
        if (dq == 0) accO0 = mfma32(ks ? A1.b : A0.b, bvf, accO0);
        else         accO1 = mfma32(ks ? A1.b : A0.b, bvf, accO1);
      }
    }
  }

  // ---- den: lane partial covers 16 of own t-half's 32; partner has rest
  den += __shfl_xor(den, 32);
  if (lane < 32) denl[wt][32 * wq + lane] = den;
  __syncthreads();

  // ---- cross-wt O partial reduction via LDS scratch (reuse Kl: 8192 f32)
  float* S = (float*)Kl;
  if (wt == 1) {
#pragma unroll
    for (int r = 0; r < 16; ++r) {
      int qr = (r & 3) + 8 * (r >> 2) + 4 * l5;  // 0..31
      S[(wq * 32 + qr) * 64 + l31] = accO0[r];
      S[(wq * 32 + qr) * 64 + 32 + l31] = accO1[r];
    }
  }
  __syncthreads();
  if (wt == 0) {
#pragma unroll
    for (int r = 0; r < 16; ++r) {
      int qr = (r & 3) + 8 * (r >> 2) + 4 * l5;
      int ql = 32 * wq + qr;
      float inv = 1.0f / (denl[0][ql] + denl[1][ql]);
      float o0 = (accO0[r] + S[(wq * 32 + qr) * 64 + l31]) * inv;
      float o1 = (accO1[r] + S[(wq * 32 + qr) * 64 + 32 + l31]) * inv;
      long long base = ((long long)(bb * 2048 + q0 + ql) * 1024) + h * 64;
      AO[base + l31] = f2b(o0);
      AO[base + 32 + l31] = f2b(o1);
    }
  }
}

// ----------------------------------------------------------- out GEMM -----
// 128x64 tiles, grid (16,32) = 512 blocks -> 2 blocks/CU (was 1). 4 waves
// in 2x2: wave covers 64 m x 32 n. Double-buffered prefetch-after-barrier.
__global__ __launch_bounds__(256, 2) void out_gemm(
    const u16* __restrict__ AO, const u16* __restrict__ wob,
    const float* __restrict__ bo, float* __restrict__ out) {
  __shared__ u16 Al[2][128][32];
  __shared__ u16 Bl[2][64][32];
  const int n0 = blockIdx.x << 6;
  const int m0 = blockIdx.y << 7;
  const int tid = threadIdx.x;
  const int wave = tid >> 6, lane = tid & 63;
  const int g = lane >> 4, c15 = lane & 15;
  const int wm = wave & 1, wn = wave >> 1;
  const u16* Wp = wob + n0 * 1024;
  const u16* Ap = AO + m0 * 1024;
  const int srow = tid >> 2;          // 0..63
  const int scol = (tid & 3) << 3;    // 0,8,16,24

  f32x4 acc[4][2];
#pragma unroll
  for (int i = 0; i < 4; i++)
#pragma unroll
    for (int j = 0; j < 2; j++) acc[i][j] = f32x4{0.f, 0.f, 0.f, 0.f};

  gld16(&Al[0][srow][scol],      Ap + srow * 1024 + scol);
  gld16(&Al[0][64 + srow][scol], Ap + (64 + srow) * 1024 + scol);
  gld16(&Bl[0][srow][scol],      Wp + srow * 1024 + scol);

  for (int k0 = 0; k0 < 1024; k0 += 32) {
    const int c = (k0 >> 5) & 1;
    __syncthreads();
    if (k0 + 32 < 1024) {
      const int kn = k0 + 32;
      gld16(&Al[c ^ 1][srow][scol],      Ap + srow * 1024 + kn + scol);
      gld16(&Al[c ^ 1][64 + srow][scol], Ap + (64 + srow) * 1024 + kn + scol);
      gld16(&Bl[c ^ 1][srow][scol],      Wp + srow * 1024 + kn + scol);
    }
    bf16x8 a[4], b[2];
#pragma unroll
    for (int i = 0; i < 4; i++)
      a[i] = *(const bf16x8*)&Al[c][wm * 64 + i * 16 + c15][g * 8];
#pragma unroll
    for (int j = 0; j < 2; j++)
      b[j] = *(const bf16x8*)&Bl[c][wn * 32 + j * 16 + c15][g * 8];
#pragma unroll
    for (int i = 0; i < 4; i++)
#pragma unroll
      for (int j = 0; j < 2; j++) acc[i][j] = mfma16(a[i], b[j], acc[i][j]);
  }
#pragma unroll
  for (int i = 0; i < 4; i++)
#pragma unroll
    for (int j = 0; j < 2; j++)
#pragma unroll
      for (int r = 0; r < 4; r++) {
        int row = m0 + wm * 64 + i * 16 + g * 4 + r;
        int col = n0 + wn * 32 + j * 16 + c15;
        out[row * 1024 + col] = acc[i][j][r] + bo[col];
      }
}

// -------------------------------------------------------------- launch -----
extern "C" void kernel_launch(void* const* d_in, const int* in_sizes, int n_in,
                              void* d_out, int out_size, void* d_ws,
                              size_t ws_size, hipStream_t stream) {
  const float* x    = (const float*)d_in[0];
  const float* Wq   = (const float*)d_in[1];
  const float* bq   = (const float*)d_in[2];
  const float* Wk   = (const float*)d_in[3];
  const float* bk   = (const float*)d_in[4];
  const float* Wv   = (const float*)d_in[5];
  const float* bv   = (const float*)d_in[6];
  const float* Wo   = (const float*)d_in[7];
  const float* bo   = (const float*)d_in[8];
  const float* Whel = (const float*)d_in[9];
  const float* bhel = (const float*)d_in[10];
  float* out = (float*)d_out;

  char* ws = (char*)d_ws;
  u16* xb   = (u16*)(ws + 0);                  //  8 MB
  u16* wb   = (u16*)(ws + 8388608);            //  6 MB (Wq|Wk|Wv)
  u16* wob  = (u16*)(ws + 14680064);           //  2 MB
  u16* whb  = (u16*)(ws + 16777216);           //  128 KB
  u16* Qcat = (u16*)(ws + 16908288);           // 16 MB  [bh][s][128]
  u16* Kcat = (u16*)(ws + 33685504);           // 16 MB
  u16* vt   = (u16*)(ws + 50462720);           //  8 MB  [bh][d][t]
  u16* AO   = (u16*)(ws + 58851328);           //  8 MB  (total ~64.1 MB)

  cast_kernel<<<dim3(8256), dim3(256), 0, stream>>>(x, Wq, Wk, Wv, Wo, Whel,
                                                    xb, wb, wob, whb);
  qkv_gemm<<<dim3(24, 32), dim3(256), 0, stream>>>(xb, wb, bq, bk, bv, whb,
                                                   bhel, Qcat, Kcat, vt);
  attn_kernel<<<dim3(16, 32), dim3(512), 0, stream>>>(Qcat, Kcat, vt, AO);
  out_gemm<<<dim3(16, 32), dim3(256), 0, stream>>>(AO, wob, bo, out);
}

// Round 8
// 224.986 us; speedup vs baseline: 1.2073x; 1.0113x over previous
//
#include <hip/hip_runtime.h>
#include <hip/hip_bf16.h>

// HelicalAttention on MI355X (gfx950).
// B=2,S=2048,E=1024,H=16,HD=64,HX=64,P=32. All heavy math in bf16 MFMA,
// fp32 accumulate. Score = (q/16)·k + (qs/8)·(ks/8) folded into one K=128
// contraction; log2(e) folded into Q so softmax uses raw exp2. Flash-style,
// no max subtraction (scores bounded).
// R8: attn P-relayout via permlane32_swap (VALU, off the LDS pipe; shfl
// fallback), bf16 pack via v_perm_b32, grid transposed for XCD-L2 locality.
// qkv hel-scramble output staged in LDS -> coalesced uint4 stores (was ~512
// scattered wave-instrs per block); Whel fragments direct from global.

typedef unsigned short u16;
typedef unsigned int u32;
typedef __attribute__((ext_vector_type(8))) __bf16 bf16x8;
typedef __attribute__((ext_vector_type(4))) float f32x4;
typedef __attribute__((ext_vector_type(16))) float f32x16;

union BFrag { u32 u[4]; bf16x8 b; };

__device__ __forceinline__ u16 f2b(float f) {
  u32 u = __float_as_uint(f);
  u32 r = (u + 0x7fffu + ((u >> 16) & 1u)) >> 16;
  return (u16)r;
}
__device__ __forceinline__ float b2f(u16 h) {
  return __uint_as_float(((u32)h) << 16);
}

__device__ __forceinline__ f32x4 mfma16(bf16x8 a, bf16x8 b, f32x4 c) {
  return __builtin_amdgcn_mfma_f32_16x16x32_bf16(a, b, c, 0, 0, 0);
}
__device__ __forceinline__ f32x16 mfma32(bf16x8 a, bf16x8 b, f32x16 c) {
  return __builtin_amdgcn_mfma_f32_32x32x16_bf16(a, b, c, 0, 0, 0);
}

// async global->LDS, 16B per lane. LDS dest = wave-uniform base + lane*16.
__device__ __forceinline__ void gld16(void* lds, const void* g) {
  __builtin_amdgcn_global_load_lds(
      (const __attribute__((address_space(1))) unsigned int*)g,
      (__attribute__((address_space(3))) unsigned int*)lds, 16, 0, 0);
}

// a' = [a.low32, b.low32], b' = [a.high32, b.high32]  (cross-half exchange)
__device__ __forceinline__ void pl32swap(u32& a, u32& b, int l5) {
#if __has_builtin(__builtin_amdgcn_permlane32_swap)
  typedef unsigned int u32x2v __attribute__((ext_vector_type(2)));
  u32x2v r = __builtin_amdgcn_permlane32_swap(a, b, false, false);
  a = r[0];
  b = r[1];
#else
  u32 ea = __shfl_xor((int)a, 32);
  u32 eb = __shfl_xor((int)b, 32);
  u32 na = l5 ? eb : a;
  u32 nb = l5 ? b : ea;
  a = na;
  b = nb;
#endif
}

#define LOG2E 1.4426950408889634f

// ---------------------------------------------------------------- cast -----
__global__ __launch_bounds__(256) void cast_kernel(
    const float* __restrict__ x,  const float* __restrict__ wq,
    const float* __restrict__ wk, const float* __restrict__ wv,
    const float* __restrict__ wo, const float* __restrict__ whel,
    u16* __restrict__ xb, u16* __restrict__ wb, u16* __restrict__ wob,
    u16* __restrict__ whb) {
  long long q = (long long)blockIdx.x * 256 + threadIdx.x;
  const float* s; u16* d; long long base;
  if (q < 1048576)      { s = x;    d = xb;            base = 0; }
  else if (q < 1310720) { s = wq;   d = wb;            base = 1048576; }
  else if (q < 1572864) { s = wk;   d = wb + 1048576;  base = 1310720; }
  else if (q < 1835008) { s = wv;   d = wb + 2097152;  base = 1572864; }
  else if (q < 2097152) { s = wo;   d = wob;           base = 1835008; }
  else                  { s = whel; d = whb;           base = 2097152; }
  long long e = (q - base) * 4;
  float4 v = *(const float4*)(s + e);
  ushort4 o;
  o.x = f2b(v.x); o.y = f2b(v.y); o.z = f2b(v.z); o.w = f2b(v.w);
  *(ushort4*)(d + e) = o;
}

// ------------------------------------------------------- QKV GEMM + hel ----
// which=0 -> Qcat[bh][s][0:64] = q*(log2e/16); which=1 -> Kcat = k;
// which=2 -> vT[bh][d][t] = v via LDS transpose (coalesced stores).
// Fused helical epilogue (which 0/1): wave's 64x64 acc quadrant = one head x
// 64 tokens; hel = acc·Whel[h]^T + bhel -> pair-normalize -> scramble staged
// in LDS (Hs) -> coalesced uint4 stores of cols [64:128).
__global__ __launch_bounds__(256, 3) void qkv_gemm(
    const u16* __restrict__ xb, const u16* __restrict__ wb,
    const float* __restrict__ bq, const float* __restrict__ bk,
    const float* __restrict__ bv, const u16* __restrict__ whb,
    const float* __restrict__ bhel,
    u16* __restrict__ Qcat, u16* __restrict__ Kcat, u16* __restrict__ vt) {
  union SM {
    struct { u16 Al[2][128][32]; u16 Bl[2][128][32]; u16 T[64][136]; } m;
    struct { u16 Th[4][32][72]; u16 Hs[2][128][64]; } e;  // 51200 B
  };
  __shared__ SM sm;
  const int nt = blockIdx.x, mt = blockIdx.y;
  const int which = nt >> 3;
  const int n0 = (nt & 7) << 7;
  const int m0 = mt << 7;
  const int tid = threadIdx.x;
  const int wave = tid >> 6, lane = tid & 63;
  const int g = lane >> 4, c15 = lane & 15;
  const int wm = wave & 1, wn = wave >> 1;
  const u16* Wp = wb + (long long)which * (1024 * 1024) + n0 * 1024;
  const u16* Ap = xb + m0 * 1024;
  const int srow = (wave * 64 + lane) >> 2;  // 0..63
  const int scol = (lane & 3) << 3;          // 0,8,16,24

  f32x4 acc[4][4];
#pragma unroll
  for (int i = 0; i < 4; i++)
#pragma unroll
    for (int j = 0; j < 4; j++) acc[i][j] = f32x4{0.f, 0.f, 0.f, 0.f};

  // prologue: stage k0=0 into buf 0
  gld16(&sm.m.Al[0][srow][scol],      Ap + srow * 1024 + scol);
  gld16(&sm.m.Al[0][64 + srow][scol], Ap + (64 + srow) * 1024 + scol);
  gld16(&sm.m.Bl[0][srow][scol],      Wp + srow * 1024 + scol);
  gld16(&sm.m.Bl[0][64 + srow][scol], Wp + (64 + srow) * 1024 + scol);

  for (int k0 = 0; k0 < 1024; k0 += 32) {
    const int c = (k0 >> 5) & 1;
    __syncthreads();  // waits DMA(k0); prefetch below had full compute to land
    if (k0 + 32 < 1024) {
      const int kn = k0 + 32;
      gld16(&sm.m.Al[c ^ 1][srow][scol],      Ap + srow * 1024 + kn + scol);
      gld16(&sm.m.Al[c ^ 1][64 + srow][scol],
            Ap + (64 + srow) * 1024 + kn + scol);
      gld16(&sm.m.Bl[c ^ 1][srow][scol],      Wp + srow * 1024 + kn + scol);
      gld16(&sm.m.Bl[c ^ 1][64 + srow][scol],
            Wp + (64 + srow) * 1024 + kn + scol);
    }
    bf16x8 a[4], b[4];
#pragma unroll
    for (int i = 0; i < 4; i++)
      a[i] = *(const bf16x8*)&sm.m.Al[c][wm * 64 + i * 16 + c15][g * 8];
#pragma unroll
    for (int j = 0; j < 4; j++)
      b[j] = *(const bf16x8*)&sm.m.Bl[c][wn * 64 + j * 16 + c15][g * 8];
#pragma unroll
    for (int i = 0; i < 4; i++)
#pragma unroll
      for (int j = 0; j < 4; j++) acc[i][j] = mfma16(a[i], b[j], acc[i][j]);
  }

  if (which == 2) {
#pragma unroll
    for (int half = 0; half < 2; ++half) {
      __syncthreads();
      if (wn == half) {
#pragma unroll
        for (int i = 0; i < 4; i++)
#pragma unroll
          for (int j = 0; j < 4; j++)
#pragma unroll
            for (int r = 0; r < 4; r++) {
              int nloc = j * 16 + c15;                  // 0..63
              int mloc = wm * 64 + i * 16 + g * 4 + r;  // 0..127
              float v = acc[i][j][r] + bv[n0 + half * 64 + nloc];
              sm.m.T[nloc][mloc] = f2b(v);
            }
      }
      __syncthreads();
#pragma unroll
      for (int it = 0; it < 4; ++it) {
        int idx = it * 256 + tid;
        int row = idx >> 4;         // 0..63
        int cm = (idx & 15) * 8;    // 0..120
        int col = n0 + half * 64 + row;
        int hh = col >> 6, dd = col & 63;
        int m = m0 + cm;
        int bb2 = m >> 11, s = m & 2047;
        *(uint4*)&vt[(((bb2 * 16 + hh) * 64) + dd) * 2048 + s] =
            *(const uint4*)&sm.m.T[row][cm];
      }
    }
    return;
  }

  // ---------------- fused helical epilogue (which 0 or 1) ----------------
  const float* bias = (which == 0) ? bq : bk;
  const float fold = (which == 0) ? (0.0625f * LOG2E) : 1.0f;
  const float osc  = (which == 0) ? (0.125f * LOG2E) : 0.125f;
  const int h0 = n0 >> 6;
  const int hsel = h0 + wn;  // wave's head (block spans 2 heads)
  u16* Dst = ((which == 0) ? Qcat : Kcat);

  // Whel B-frags direct from global (once per block)
  bf16x8 wf[2][4];  // [kh][nf]
#pragma unroll
  for (int kh = 0; kh < 2; ++kh)
#pragma unroll
    for (int nf = 0; nf < 4; ++nf)
      wf[kh][nf] = *(const bf16x8*)(whb + hsel * 4096 + (nf * 16 + c15) * 64 +
                                    kh * 32 + g * 8);

  __syncthreads();  // all main-loop LDS reads done; safe to repurpose
  const int bb2 = m0 >> 11;
  const int ubase = (m0 & 2047) >> 1;

#pragma unroll
  for (int half = 0; half < 2; ++half) {
    // main output write (cols [0:64)) + per-wave Th tile (raw bf16, no fold)
#pragma unroll
    for (int i2 = 0; i2 < 2; ++i2) {
      int i = half * 2 + i2;
#pragma unroll
      for (int j = 0; j < 4; ++j)
#pragma unroll
        for (int r = 0; r < 4; ++r) {
          int row = m0 + wm * 64 + i * 16 + g * 4 + r;  // token 0..4095
          int col = n0 + wn * 64 + j * 16 + c15;
          float vraw = acc[i][j][r] + bias[col];
          int bb = row >> 11, s = row & 2047;
          int d = col & 63;
          Dst[(((long long)(bb * 16 + hsel) * 2048) + s) * 128 + d] =
              f2b(vraw * fold);
          sm.e.Th[wave][i2 * 16 + g * 4 + r][j * 16 + c15] = f2b(vraw);
        }
    }
    // hel = Th(32 tok x 64 d) · Whel[h]^T   [Th wave-private, in-order LDS]
    f32x4 hacc[2][4];
#pragma unroll
    for (int mf = 0; mf < 2; ++mf)
#pragma unroll
      for (int nf = 0; nf < 4; ++nf) hacc[mf][nf] = f32x4{0.f, 0.f, 0.f, 0.f};
#pragma unroll
    for (int kh = 0; kh < 2; ++kh) {
      bf16x8 a0 = *(const bf16x8*)&sm.e.Th[wave][c15][kh * 32 + g * 8];
      bf16x8 a1 = *(const bf16x8*)&sm.e.Th[wave][16 + c15][kh * 32 + g * 8];
#pragma unroll
      for (int nf = 0; nf < 4; ++nf) {
        hacc[0][nf] = mfma16(a0, wf[kh][nf], hacc[0][nf]);
        hacc[1][nf] = mfma16(a1, wf[kh][nf], hacc[1][nf]);
      }
    }
    // + bhel, pair-normalize (partner e^1 = lane^1), scramble-stage into Hs
#pragma unroll
    for (int mf = 0; mf < 2; ++mf)
#pragma unroll
      for (int nf = 0; nf < 4; ++nf)
#pragma unroll
        for (int r = 0; r < 4; ++r) {
          int e = nf * 16 + c15;
          float v = hacc[mf][nf][r] + bhel[hsel * 64 + e];
          float pp = __shfl_xor(v, 1);
          float nn = sqrtf(v * v + pp * pp);
          float o = v / fmaxf(nn, 1e-12f) * osc;
          int tl = wm * 64 + half * 32 + mf * 16 + g * 4 + r;  // token-local
          sm.e.Hs[wn][(e & 1) * 64 + (tl >> 1)][(e & ~1) | (tl & 1)] = f2b(o);
        }
  }
  __syncthreads();
  // coalesced stores of hel region: 2 heads x 128 Hs-rows x 8 uint4 chunks
#pragma unroll
  for (int it = 0; it < 8; ++it) {
    int idx = it * 256 + tid;  // 0..2047
    int hh = idx >> 10;
    int hr = (idx >> 3) & 127;
    int ck = idx & 7;
    int coord = hr >> 6, ul = hr & 63;
    int row_out = coord * 1024 + ubase + ul;
    *(uint4*)&Dst[(((long long)(bb2 * 16 + h0 + hh) * 2048) + row_out) * 128 +
                  64 + ck * 8] = *(const uint4*)&sm.e.Hs[hh][hr][ck * 8];
  }
}

// ----------------------------------------------------------- attention -----
// Per (bh, 128-q tile), 8 waves: wq=w&3, wt=w>>2 (t half). Pipelined
// single-barrier K-loop over 32 tiles of 64 t; P in registers (C->A relayout
// via permlane32_swap — VALU pipe); cross-wt O partial sum at end via LDS.
// Grid (bh, qt) so each XCD's K/V working set (~3 MB) fits its L2.
__global__ __launch_bounds__(512, 4) void attn_kernel(
    const u16* __restrict__ Qcat, const u16* __restrict__ Kcat,
    const u16* __restrict__ vt, u16* __restrict__ AO) {
  __shared__ u16 Kl[2][64][128];   // [buf][t-row][cat 16 chunks, swizzled]
  __shared__ u16 Vl[2][64][64];    // [buf][d-row][t 8 chunks, swizzled]
  __shared__ float denl[2][128];   // [wt][q-local]
  const int bh = blockIdx.x, qt = blockIdx.y;
  const int bb = bh >> 4, h = bh & 15;
  const int q0 = qt << 7;
  const int tid = threadIdx.x;
  const int w = tid >> 6, lane = tid & 63;
  const int wq = w & 3, wt = w >> 2;
  const int l31 = lane & 31, l5 = lane >> 5;
  const u16* Qb = Qcat + (long long)bh * (2048 * 128);
  const u16* Kb = Kcat + (long long)bh * (2048 * 128);
  const u16* Vb = vt + (long long)bh * (64 * 2048);

  // Q B-frags: n = l31 -> q = q0+32wq+l31; k = ks*16+l5*8+j
  bf16x8 qf[8];
  {
    const u16* qrow = Qb + (q0 + 32 * wq + l31) * 128 + l5 * 8;
#pragma unroll
    for (int ks = 0; ks < 8; ++ks) qf[ks] = *(const bf16x8*)(qrow + ks * 16);
  }

  // staging address precompute (XOR-swizzled 16B chunks)
  const int ll = tid;                 // 0..511
  const int krow0 = ll >> 4;          // pass 0: rows 0..31
  const int kp = ll & 15;
  const int ksrc0 = (kp & 8) | ((kp & 7) ^ (krow0 & 7));
  const int krow1 = 32 + krow0;       // pass 1: rows 32..63
  const int ksrc1 = (kp & 8) | ((kp & 7) ^ (krow1 & 7));
  const int vd = ll >> 3;
  const int vsrc = (ll & 7) ^ (vd & 7);

  // prologue: stage tile 0 into buf 0
  gld16(((u16*)Kl[0]) + ll * 8,        Kb + krow0 * 128 + ksrc0 * 8);
  gld16(((u16*)Kl[0]) + 4096 + ll * 8, Kb + krow1 * 128 + ksrc1 * 8);
  gld16(((u16*)Vl[0]) + ll * 8,        Vb + vd * 2048 + vsrc * 8);

  f32x16 accO0, accO1;
#pragma unroll
  for (int i = 0; i < 16; ++i) { accO0[i] = 0.f; accO1[i] = 0.f; }
  float den = 0.f;

  const int krow = 32 * wt + l31;  // S-phase A row (t-local)
  const int kr7 = krow & 7;

  for (int t = 0; t < 32; ++t) {
    const int cur = t & 1;
    __syncthreads();  // DMA(tile t) complete; readers of buf cur^1 done
    if (t + 1 < 32) {
      const int t1 = (t + 1) << 6;
      u16* Kd = (u16*)Kl[cur ^ 1];
      gld16(Kd + ll * 8,        Kb + (t1 + krow0) * 128 + ksrc0 * 8);
      gld16(Kd + 4096 + ll * 8, Kb + (t1 + krow1) * 128 + ksrc1 * 8);
      gld16(((u16*)Vl[cur ^ 1]) + ll * 8, Vb + vd * 2048 + t1 + vsrc * 8);
    }

    // ---- S^T[t-local 32wt..][q 32wq..] : 8 k-steps of 16 over cat=128
    f32x16 accS;
#pragma unroll
    for (int i = 0; i < 16; ++i) accS[i] = 0.f;
#pragma unroll
    for (int ks = 0; ks < 8; ++ks) {
      int lc = 2 * ks + l5;
      int p = (lc & 8) | ((lc & 7) ^ kr7);
      bf16x8 ak = *(const bf16x8*)&Kl[cur][krow][p * 8];
      accS = mfma32(ak, qf[ks], accS);
    }

    // ---- exp2 -> packed bf16 P (regs, v_perm pack); per-lane den partial
    u32 D0[2], D1[2], D2[2], D3[2];
#pragma unroll
    for (int rr = 0; rr < 4; ++rr) {
      float p0 = __builtin_amdgcn_exp2f(accS[4 * rr + 0]);
      float p1 = __builtin_amdgcn_exp2f(accS[4 * rr + 1]);
      float p2 = __builtin_amdgcn_exp2f(accS[4 * rr + 2]);
      float p3 = __builtin_amdgcn_exp2f(accS[4 * rr + 3]);
      den += (p0 + p1) + (p2 + p3);
      u32 lo = __builtin_amdgcn_perm(__float_as_uint(p1), __float_as_uint(p0),
                                     0x07060302u);
      u32 hi = __builtin_amdgcn_perm(__float_as_uint(p3), __float_as_uint(p2),
                                     0x07060302u);
      if (rr == 0) { D0[0] = lo; D0[1] = hi; }
      else if (rr == 1) { D1[0] = lo; D1[1] = hi; }
      else if (rr == 2) { D2[0] = lo; D2[1] = hi; }
      else { D3[0] = lo; D3[1] = hi; }
    }
    // cross-half exchange: build A-frags (m=q, k=t-local within own half)
    BFrag A0, A1;
    A0.u[0] = D0[0]; A0.u[2] = D1[0]; pl32swap(A0.u[0], A0.u[2], l5);
    A0.u[1] = D0[1]; A0.u[3] = D1[1]; pl32swap(A0.u[1], A0.u[3], l5);
    A1.u[0] = D2[0]; A1.u[2] = D3[0]; pl32swap(A1.u[0], A1.u[2], l5);
    A1.u[1] = D2[1]; A1.u[3] = D3[1]; pl32swap(A1.u[1], A1.u[3], l5);

    // ---- O_partial[q 32wq..][d 0..63] += P · V over OWN t-half (k=32)
#pragma unroll
    for (int dq = 0; dq < 2; ++dq) {
      int d = 32 * dq + l31;
      int d7 = d & 7;
#pragma unroll
      for (int ks = 0; ks < 2; ++ks) {
        int lc = 4 * wt + 2 * ks + l5;
        bf16x8 bvf = *(const bf16x8*)&Vl[cur][d][((lc ^ d7) & 7) * 8];
        if (dq == 0) accO0 = mfma32(ks ? A1.b : A0.b, bvf, accO0);
        else         accO1 = mfma32(ks ? A1.b : A0.b, bvf, accO1);
      }
    }
  }

  // ---- den: lane partial covers 16 of own t-half's 32; partner has rest
  den += __shfl_xor(den, 32);
  if (lane < 32) denl[wt][32 * wq + lane] = den;
  __syncthreads();

  // ---- cross-wt O partial reduction via LDS scratch (reuse Kl: 8192 f32)
  float* S = (float*)Kl;
  if (wt == 1) {
#pragma unroll
    for (int r = 0; r < 16; ++r) {
      int qr = (r & 3) + 8 * (r >> 2) + 4 * l5;  // 0..31
      S[(wq * 32 + qr) * 64 + l31] = accO0[r];
      S[(wq * 32 + qr) * 64 + 32 + l31] = accO1[r];
    }
  }
  __syncthreads();
  if (wt == 0) {
#pragma unroll
    for (int r = 0; r < 16; ++r) {
      int qr = (r & 3) + 8 * (r >> 2) + 4 * l5;
      int ql = 32 * wq + qr;
      float inv = 1.0f / (denl[0][ql] + denl[1][ql]);
      float o0 = (accO0[r] + S[(wq * 32 + qr) * 64 + l31]) * inv;
      float o1 = (accO1[r] + S[(wq * 32 + qr) * 64 + 32 + l31]) * inv;
      long long base = ((long long)(bb * 2048 + q0 + ql) * 1024) + h * 64;
      AO[base + l31] = f2b(o0);
      AO[base + 32 + l31] = f2b(o1);
    }
  }
}

// ----------------------------------------------------------- out GEMM -----
// 128x64 tiles, grid (16,32) = 512 blocks -> 2 blocks/CU. 4 waves in 2x2:
// wave covers 64 m x 32 n. Double-buffered prefetch-after-barrier.
__global__ __launch_bounds__(256, 2) void out_gemm(
    const u16* __restrict__ AO, const u16* __restrict__ wob,
    const float* __restrict__ bo, float* __restrict__ out) {
  __shared__ u16 Al[2][128][32];
  __shared__ u16 Bl[2][64][32];
  const int n0 = blockIdx.x << 6;
  const int m0 = blockIdx.y << 7;
  const int tid = threadIdx.x;
  const int wave = tid >> 6, lane = tid & 63;
  const int g = lane >> 4, c15 = lane & 15;
  const int wm = wave & 1, wn = wave >> 1;
  const u16* Wp = wob + n0 * 1024;
  const u16* Ap = AO + m0 * 1024;
  const int srow = tid >> 2;          // 0..63
  const int scol = (tid & 3) << 3;    // 0,8,16,24

  f32x4 acc[4][2];
#pragma unroll
  for (int i = 0; i < 4; i++)
#pragma unroll
    for (int j = 0; j < 2; j++) acc[i][j] = f32x4{0.f, 0.f, 0.f, 0.f};

  gld16(&Al[0][srow][scol],      Ap + srow * 1024 + scol);
  gld16(&Al[0][64 + srow][scol], Ap + (64 + srow) * 1024 + scol);
  gld16(&Bl[0][srow][scol],      Wp + srow * 1024 + scol);

  for (int k0 = 0; k0 < 1024; k0 += 32) {
    const int c = (k0 >> 5) & 1;
    __syncthreads();
    if (k0 + 32 < 1024) {
      const int kn = k0 + 32;
      gld16(&Al[c ^ 1][srow][scol],      Ap + srow * 1024 + kn + scol);
      gld16(&Al[c ^ 1][64 + srow][scol], Ap + (64 + srow) * 1024 + kn + scol);
      gld16(&Bl[c ^ 1][srow][scol],      Wp + srow * 1024 + kn + scol);
    }
    bf16x8 a[4], b[2];
#pragma unroll
    for (int i = 0; i < 4; i++)
      a[i] = *(const bf16x8*)&Al[c][wm * 64 + i * 16 + c15][g * 8];
#pragma unroll
    for (int j = 0; j < 2; j++)
      b[j] = *(const bf16x8*)&Bl[c][wn * 32 + j * 16 + c15][g * 8];
#pragma unroll
    for (int i = 0; i < 4; i++)
#pragma unroll
      for (int j = 0; j < 2; j++) acc[i][j] = mfma16(a[i], b[j], acc[i][j]);
  }
#pragma unroll
  for (int i = 0; i < 4; i++)
#pragma unroll
    for (int j = 0; j < 2; j++)
#pragma unroll
      for (int r = 0; r < 4; r++) {
        int row = m0 + wm * 64 + i * 16 + g * 4 + r;
        int col = n0 + wn * 32 + j * 16 + c15;
        out[row * 1024 + col] = acc[i][j][r] + bo[col];
      }
}

// -------------------------------------------------------------- launch -----
extern "C" void kernel_launch(void* const* d_in, const int* in_sizes, int n_in,
                              void* d_out, int out_size, void* d_ws,
                              size_t ws_size, hipStream_t stream) {
  const float* x    = (const float*)d_in[0];
  const float* Wq   = (const float*)d_in[1];
  const float* bq   = (const float*)d_in[2];
  const float* Wk   = (const float*)d_in[3];
  const float* bk   = (const float*)d_in[4];
  const float* Wv   = (const float*)d_in[5];
  const float* bv   = (const float*)d_in[6];
  const float* Wo   = (const float*)d_in[7];
  const float* bo   = (const float*)d_in[8];
  const float* Whel = (const float*)d_in[9];
  const float* bhel = (const float*)d_in[10];
  float* out = (float*)d_out;

  char* ws = (char*)d_ws;
  u16* xb   = (u16*)(ws + 0);                  //  8 MB
  u16* wb   = (u16*)(ws + 8388608);            //  6 MB (Wq|Wk|Wv)
  u16* wob  = (u16*)(ws + 14680064);           //  2 MB
  u16* whb  = (u16*)(ws + 16777216);           //  128 KB
  u16* Qcat = (u16*)(ws + 16908288);           // 16 MB  [bh][s][128]
  u16* Kcat = (u16*)(ws + 33685504);           // 16 MB
  u16* vt   = (u16*)(ws + 50462720);           //  8 MB  [bh][d][t]
  u16* AO   = (u16*)(ws + 58851328);           //  8 MB  (total ~64.1 MB)

  cast_kernel<<<dim3(8256), dim3(256), 0, stream>>>(x, Wq, Wk, Wv, Wo, Whel,
                                                    xb, wb, wob, whb);
  qkv_gemm<<<dim3(24, 32), dim3(256), 0, stream>>>(xb, wb, bq, bk, bv, whb,
                                                   bhel, Qcat, Kcat, vt);
  attn_kernel<<<dim3(32, 16), dim3(512), 0, stream>>>(Qcat, Kcat, vt, AO);
  out_gemm<<<dim3(16, 32), dim3(256), 0, stream>>>(AO, wob, bo, out);
}